// Round 1
// baseline (443.290 us; speedup 1.0000x reference)
//
#include <hip/hip_runtime.h>

// Problem constants (from reference): S=2, B=100, C=5, H=W=224.
#define SS 2
#define BB 100
#define CC 5
#define HH 224
#define WW 224
#define HW (HH * WW)          // 50176
#define BCHUNK 20             // patches per block
#define NCHUNK (BB / BCHUNK)  // 5
#define PIXBLOCKS ((SS * HW) / 256)  // 392, exact

__global__ __launch_bounds__(256) void k_zero(float* __restrict__ out, int n) {
    int i = blockIdx.x * blockDim.x + threadIdx.x;
    if (i < n) out[i] = 0.0f;
}

__global__ __launch_bounds__(256) void k_clamp(float* __restrict__ out, int n) {
    int i = blockIdx.x * blockDim.x + threadIdx.x;
    if (i < n) {
        float v = out[i];
        out[i] = fminf(fmaxf(v, 0.0f), 1.0f);
    }
}

// Each block: 256 output pixels (one s, contiguous h,w) x one chunk of 20 patches.
// Accumulates premultiplied RGB into d_out with atomics.
__global__ __launch_bounds__(256) void k_main(
    const float* __restrict__ patches,
    const float* __restrict__ tr, const float* __restrict__ rot,
    const float* __restrict__ sc, const float* __restrict__ sq,
    const float* __restrict__ sh, const float* __restrict__ re,
    const float* __restrict__ gr, const float* __restrict__ bl,
    float* __restrict__ out)
{
    __shared__ float tb[BCHUNK][9];  // t00,t01,t02,t10,t11,t12,r,g,b

    const int pb    = blockIdx.x % PIXBLOCKS;  // adjacent blocks -> adjacent pixels (L2 locality)
    const int chunk = blockIdx.x / PIXBLOCKS;

    const int pix = pb * 256 + threadIdx.x;
    const int s   = pix / HW;              // uniform per block (196 blocks per s, exact)
    const int hw  = pix - s * HW;
    const int h   = hw / WW;
    const int w   = hw - h * WW;

    if (threadIdx.x < BCHUNK) {
        const int b = chunk * BCHUNK + threadIdx.x;
        const int i = s * BB + b;
        const float a  = sc[i] * sq[i];
        const float s2 = sc[i];
        float sn, cn;
        sincosf(rot[i], &sn, &cn);
        const float shv = sh[i];
        const float tx = tr[2 * i], ty = tr[2 * i + 1];
        const float t00 = a * cn;
        const float t01 = a * (cn * shv - sn);
        const float t10 = s2 * sn;
        const float t11 = s2 * (sn * shv + cn);
        tb[threadIdx.x][0] = t00;
        tb[threadIdx.x][1] = t01;
        tb[threadIdx.x][2] = t00 * tx + t01 * ty;
        tb[threadIdx.x][3] = t10;
        tb[threadIdx.x][4] = t11;
        tb[threadIdx.x][5] = t10 * tx + t11 * ty;
        tb[threadIdx.x][6] = re[i];
        tb[threadIdx.x][7] = gr[i];
        tb[threadIdx.x][8] = bl[i];
    }
    __syncthreads();

    const float xs = -1.0f + 2.0f * (float)w / (float)(WW - 1);
    const float ys = -1.0f + 2.0f * (float)h / (float)(HH - 1);

    float accR = 0.0f, accG = 0.0f, accB = 0.0f;

    // base of this s's patch block
    const float* Pbase = patches + (size_t)s * BB * CC * HW
                                 + (size_t)chunk * BCHUNK * CC * HW;

    for (int bb = 0; bb < BCHUNK; ++bb) {
        const float gx = tb[bb][0] * xs + tb[bb][1] * ys + tb[bb][2];
        const float gy = tb[bb][3] * xs + tb[bb][4] * ys + tb[bb][5];
        const float ix = (gx + 1.0f) * 0.5f * (float)(WW - 1);
        const float iy = (gy + 1.0f) * 0.5f * (float)(HH - 1);

        // fully-outside => zero contribution, skip all loads
        if (ix <= -1.0f || ix >= (float)WW || iy <= -1.0f || iy >= (float)HH) continue;

        const float ix0f = floorf(ix), iy0f = floorf(iy);
        const float wx = ix - ix0f, wy = iy - iy0f;
        const int ix0 = (int)ix0f, iy0 = (int)iy0f;   // in [-1, W-1] / [-1, H-1]

        const int x0 = max(ix0, 0);
        const int x1 = min(ix0 + 1, WW - 1);
        const int y0 = max(iy0, 0);
        const int y1 = min(iy0 + 1, HH - 1);

        const float vx0 = (ix0 >= 0)       ? 1.0f : 0.0f;
        const float vx1 = (ix0 + 1 < WW)   ? 1.0f : 0.0f;
        const float vy0 = (iy0 >= 0)       ? 1.0f : 0.0f;
        const float vy1 = (iy0 + 1 < HH)   ? 1.0f : 0.0f;

        const float w00 = (1.0f - wx) * (1.0f - wy) * vx0 * vy0;
        const float w01 = wx * (1.0f - wy) * vx1 * vy0;
        const float w10 = (1.0f - wx) * wy * vx0 * vy1;
        const float w11 = wx * wy * vx1 * vy1;

        const int i00 = y0 * WW + x0;
        const int i01 = y0 * WW + x1;
        const int i10 = y1 * WW + x0;
        const int i11 = y1 * WW + x1;

        const float* Pb = Pbase + (size_t)bb * CC * HW;

        float chv[4];
        #pragma unroll
        for (int c = 0; c < 4; ++c) {   // channel 4 (orders) never reaches the output
            const float* Pc = Pb + (size_t)c * HW;
            chv[c] = Pc[i00] * w00 + Pc[i01] * w01 + Pc[i10] * w10 + Pc[i11] * w11;
        }
        const float alpha = chv[3];
        accR += chv[0] * tb[bb][6] * alpha;
        accG += chv[1] * tb[bb][7] * alpha;
        accB += chv[2] * tb[bb][8] * alpha;
    }

    const size_t o = (size_t)pix * 3;
    atomicAdd(&out[o + 0], accR);
    atomicAdd(&out[o + 1], accG);
    atomicAdd(&out[o + 2], accB);
}

extern "C" void kernel_launch(void* const* d_in, const int* in_sizes, int n_in,
                              void* d_out, int out_size, void* d_ws, size_t ws_size,
                              hipStream_t stream) {
    const float* patches = (const float*)d_in[0];
    const float* tr      = (const float*)d_in[1];
    const float* rot     = (const float*)d_in[2];
    const float* sc      = (const float*)d_in[3];
    const float* sq      = (const float*)d_in[4];
    const float* sh      = (const float*)d_in[5];
    const float* re      = (const float*)d_in[6];
    const float* gr      = (const float*)d_in[7];
    const float* bl      = (const float*)d_in[8];
    // d_in[9] (orders) is mathematically dead: channel 4 never reaches the RGB output.
    float* out = (float*)d_out;

    const int nblk = (out_size + 255) / 256;
    k_zero<<<nblk, 256, 0, stream>>>(out, out_size);
    k_main<<<PIXBLOCKS * NCHUNK, 256, 0, stream>>>(patches, tr, rot, sc, sq, sh, re, gr, bl, out);
    k_clamp<<<nblk, 256, 0, stream>>>(out, out_size);
}

// Round 5
// 361.660 us; speedup vs baseline: 1.2257x; 1.2257x over previous
//
#include <hip/hip_runtime.h>

// Problem constants (from reference): S=2, B=100, C=5, H=W=224.
#define SS 2
#define BB 100
#define CC 5
#define HH 224
#define WW 224
#define HW (HH * WW)            // 50176
#define OUTN (SS * HW * 3)      // 301056
#define BCHUNK 20               // patches per block
#define NCHUNK (BB / BCHUNK)    // 5
#define TILE 16                 // 16x16 output pixels per block
#define TPD (WW / TILE)         // 14 tiles per dimension (exact)
#define TILES_PER_S (TPD * TPD) // 196

// Reduce 5 chunk-partials from ws -> clamped out.
__global__ __launch_bounds__(256) void k_reduce(const float* __restrict__ ws,
                                                float* __restrict__ out, int n) {
    int i = blockIdx.x * blockDim.x + threadIdx.x;
    if (i < n) {
        float v = 0.0f;
        #pragma unroll
        for (int c = 0; c < NCHUNK; ++c) v += ws[(size_t)c * OUTN + i];
        out[i] = fminf(fmaxf(v, 0.0f), 1.0f);
    }
}

// Fallback-path helpers (used only if ws_size is too small).
__global__ __launch_bounds__(256) void k_zero(float* __restrict__ out, int n) {
    int i = blockIdx.x * blockDim.x + threadIdx.x;
    if (i < n) out[i] = 0.0f;
}
__global__ __launch_bounds__(256) void k_clamp(float* __restrict__ out, int n) {
    int i = blockIdx.x * blockDim.x + threadIdx.x;
    if (i < n) { float v = out[i]; out[i] = fminf(fmaxf(v, 0.0f), 1.0f); }
}

// Each block: one 16x16 output tile (one s) x one chunk of 20 patches.
// MODE_WS=true: plain stores of per-chunk partials into ws.
// MODE_WS=false: atomicAdd into out (requires pre-zeroed out).
template <bool MODE_WS>
__global__ __launch_bounds__(256) void k_main(
    const float* __restrict__ patches,
    const float* __restrict__ tr, const float* __restrict__ rot,
    const float* __restrict__ sc, const float* __restrict__ sq,
    const float* __restrict__ sh, const float* __restrict__ re,
    const float* __restrict__ gr, const float* __restrict__ bl,
    float* __restrict__ dst)
{
    __shared__ float tb[BCHUNK][9];  // t00,t01,t02,t10,t11,t12,r,g,b

    // chunk-major outer: adjacent blocks share transforms + neighboring texels
    const int rem   = blockIdx.x % (SS * TILES_PER_S);
    const int chunk = blockIdx.x / (SS * TILES_PER_S);
    const int s     = rem / TILES_PER_S;
    const int tile  = rem % TILES_PER_S;
    const int tileY = tile / TPD;
    const int tileX = tile % TPD;

    const int tx = threadIdx.x & (TILE - 1);
    const int ty = threadIdx.x >> 4;
    const int w  = tileX * TILE + tx;
    const int h  = tileY * TILE + ty;

    if (threadIdx.x < BCHUNK) {
        const int b = chunk * BCHUNK + threadIdx.x;
        const int i = s * BB + b;
        const float a  = sc[i] * sq[i];
        const float s2 = sc[i];
        float sn, cn;
        sincosf(rot[i], &sn, &cn);
        const float shv = sh[i];
        const float tx_ = tr[2 * i], ty_ = tr[2 * i + 1];
        const float t00 = a * cn;
        const float t01 = a * (cn * shv - sn);
        const float t10 = s2 * sn;
        const float t11 = s2 * (sn * shv + cn);
        tb[threadIdx.x][0] = t00;
        tb[threadIdx.x][1] = t01;
        tb[threadIdx.x][2] = t00 * tx_ + t01 * ty_;
        tb[threadIdx.x][3] = t10;
        tb[threadIdx.x][4] = t11;
        tb[threadIdx.x][5] = t10 * tx_ + t11 * ty_;
        tb[threadIdx.x][6] = re[i];
        tb[threadIdx.x][7] = gr[i];
        tb[threadIdx.x][8] = bl[i];
    }
    __syncthreads();

    const float xs = -1.0f + 2.0f * (float)w / (float)(WW - 1);
    const float ys = -1.0f + 2.0f * (float)h / (float)(HH - 1);

    float accR = 0.0f, accG = 0.0f, accB = 0.0f;

    const float* Pbase = patches + (size_t)s * BB * CC * HW
                                 + (size_t)chunk * BCHUNK * CC * HW;

    for (int bb = 0; bb < BCHUNK; ++bb) {
        const float gx = tb[bb][0] * xs + tb[bb][1] * ys + tb[bb][2];
        const float gy = tb[bb][3] * xs + tb[bb][4] * ys + tb[bb][5];
        const float ix = (gx + 1.0f) * 0.5f * (float)(WW - 1);
        const float iy = (gy + 1.0f) * 0.5f * (float)(HH - 1);

        // fully-outside => zero contribution, skip all loads
        if (ix <= -1.0f || ix >= (float)WW || iy <= -1.0f || iy >= (float)HH) continue;

        const float ix0f = floorf(ix), iy0f = floorf(iy);
        const float wx = ix - ix0f, wy = iy - iy0f;
        const int ix0 = (int)ix0f, iy0 = (int)iy0f;   // in [-1, W-1] / [-1, H-1]

        const int x0 = max(ix0, 0);
        const int x1 = min(ix0 + 1, WW - 1);
        const int y0 = max(iy0, 0);
        const int y1 = min(iy0 + 1, HH - 1);

        const float vx0 = (ix0 >= 0)     ? 1.0f : 0.0f;
        const float vx1 = (ix0 + 1 < WW) ? 1.0f : 0.0f;
        const float vy0 = (iy0 >= 0)     ? 1.0f : 0.0f;
        const float vy1 = (iy0 + 1 < HH) ? 1.0f : 0.0f;

        const float w00 = (1.0f - wx) * (1.0f - wy) * vx0 * vy0;
        const float w01 = wx * (1.0f - wy) * vx1 * vy0;
        const float w10 = (1.0f - wx) * wy * vx0 * vy1;
        const float w11 = wx * wy * vx1 * vy1;

        const int i00 = y0 * WW + x0;
        const int i01 = y0 * WW + x1;
        const int i10 = y1 * WW + x0;
        const int i11 = y1 * WW + x1;

        const float* Pb = Pbase + (size_t)bb * CC * HW;

        float chv[4];
        #pragma unroll
        for (int c = 0; c < 4; ++c) {   // channel 4 (orders) never reaches the output
            const float* Pc = Pb + (size_t)c * HW;
            chv[c] = Pc[i00] * w00 + Pc[i01] * w01 + Pc[i10] * w10 + Pc[i11] * w11;
        }
        const float alpha = chv[3];
        accR += chv[0] * tb[bb][6] * alpha;
        accG += chv[1] * tb[bb][7] * alpha;
        accB += chv[2] * tb[bb][8] * alpha;
    }

    const int pix = s * HW + h * WW + w;
    const size_t o = (size_t)pix * 3;
    if (MODE_WS) {
        float* p = dst + (size_t)chunk * OUTN + o;
        p[0] = accR; p[1] = accG; p[2] = accB;
    } else {
        atomicAdd(&dst[o + 0], accR);
        atomicAdd(&dst[o + 1], accG);
        atomicAdd(&dst[o + 2], accB);
    }
}

extern "C" void kernel_launch(void* const* d_in, const int* in_sizes, int n_in,
                              void* d_out, int out_size, void* d_ws, size_t ws_size,
                              hipStream_t stream) {
    const float* patches = (const float*)d_in[0];
    const float* tr      = (const float*)d_in[1];
    const float* rot     = (const float*)d_in[2];
    const float* sc      = (const float*)d_in[3];
    const float* sq      = (const float*)d_in[4];
    const float* sh      = (const float*)d_in[5];
    const float* re      = (const float*)d_in[6];
    const float* gr      = (const float*)d_in[7];
    const float* bl      = (const float*)d_in[8];
    // d_in[9] (orders) is mathematically dead: channel 4 never reaches the RGB output.
    float* out = (float*)d_out;

    const int nblkOut = (out_size + 255) / 256;
    const int grid    = SS * TILES_PER_S * NCHUNK;  // 1960

    if (ws_size >= (size_t)NCHUNK * OUTN * sizeof(float)) {
        float* ws = (float*)d_ws;
        k_main<true><<<grid, 256, 0, stream>>>(patches, tr, rot, sc, sq, sh, re, gr, bl, ws);
        k_reduce<<<nblkOut, 256, 0, stream>>>(ws, out, out_size);
    } else {
        k_zero<<<nblkOut, 256, 0, stream>>>(out, out_size);
        k_main<false><<<grid, 256, 0, stream>>>(patches, tr, rot, sc, sq, sh, re, gr, bl, out);
        k_clamp<<<nblkOut, 256, 0, stream>>>(out, out_size);
    }
}

// Round 11
// 334.246 us; speedup vs baseline: 1.3262x; 1.0820x over previous
//
#include <hip/hip_runtime.h>

// Problem constants (from reference): S=2, B=100, C=5, H=W=224.
#define SS 2
#define BB 100
#define CC 5
#define HH 224
#define WW 224
#define HW (HH * WW)            // 50176
#define IMGN (SS * BB)          // 200
#define OUTN (SS * HW * 3)      // 301056
#define BCHUNK 10               // patches per block
#define NCHUNK (BB / BCHUNK)    // 10
#define TILE 16                 // 16x16 output pixels per block
#define TPD (WW / TILE)         // 14
#define TILES_PER_S (TPD * TPD) // 196

#define RGBA_FLOATS ((size_t)IMGN * HW * 4)   // 40,140,800 floats = 160.56 MB
#define PART_FLOATS ((size_t)NCHUNK * OUTN)   // 3,010,560 floats = 12.04 MB

// ---- repack planar [img][c][hw] (c=0..3) -> AoS float4 [img][hw] ----
__global__ __launch_bounds__(256) void k_repack(const float* __restrict__ patches,
                                                float4* __restrict__ rgba) {
    const int i = blockIdx.x * 256 + threadIdx.x;      // texel index, 10,035,200 total (exact grid)
    const int img = i / HW;
    const int hw  = i - img * HW;
    const float* base = patches + (size_t)img * CC * HW + hw;
    float4 v;
    v.x = base[0];
    v.y = base[HW];
    v.z = base[2 * HW];
    v.w = base[3 * HW];
    rgba[i] = v;
}

// ---- reduce NCHUNK chunk-partials -> clamped out ----
__global__ __launch_bounds__(256) void k_reduce(const float* __restrict__ ws,
                                                float* __restrict__ out, int n) {
    int i = blockIdx.x * blockDim.x + threadIdx.x;
    if (i < n) {
        float v = 0.0f;
        #pragma unroll
        for (int c = 0; c < NCHUNK; ++c) v += ws[(size_t)c * OUTN + i];
        out[i] = fminf(fmaxf(v, 0.0f), 1.0f);
    }
}

__global__ __launch_bounds__(256) void k_zero(float* __restrict__ out, int n) {
    int i = blockIdx.x * blockDim.x + threadIdx.x;
    if (i < n) out[i] = 0.0f;
}
__global__ __launch_bounds__(256) void k_clamp(float* __restrict__ out, int n) {
    int i = blockIdx.x * blockDim.x + threadIdx.x;
    if (i < n) { float v = out[i]; out[i] = fminf(fmaxf(v, 0.0f), 1.0f); }
}

// ---- shared transform setup (device inline) ----
__device__ __forceinline__ void setup_tb(float (*tb)[9], int s, int chunk,
    const float* tr, const float* rot, const float* sc, const float* sq,
    const float* sh, const float* re, const float* gr, const float* bl) {
    if (threadIdx.x < BCHUNK) {
        const int b = chunk * BCHUNK + threadIdx.x;
        const int i = s * BB + b;
        const float a  = sc[i] * sq[i];
        const float s2 = sc[i];
        float sn, cn;
        sincosf(rot[i], &sn, &cn);
        const float shv = sh[i];
        const float tx_ = tr[2 * i], ty_ = tr[2 * i + 1];
        const float t00 = a * cn;
        const float t01 = a * (cn * shv - sn);
        const float t10 = s2 * sn;
        const float t11 = s2 * (sn * shv + cn);
        tb[threadIdx.x][0] = t00;
        tb[threadIdx.x][1] = t01;
        tb[threadIdx.x][2] = t00 * tx_ + t01 * ty_;
        tb[threadIdx.x][3] = t10;
        tb[threadIdx.x][4] = t11;
        tb[threadIdx.x][5] = t10 * tx_ + t11 * ty_;
        tb[threadIdx.x][6] = re[i];
        tb[threadIdx.x][7] = gr[i];
        tb[threadIdx.x][8] = bl[i];
    }
}

// ---- main, RGBA AoS path: one dwordx4 gather per bilinear corner ----
__global__ __launch_bounds__(256) void k_main_rgba(
    const float4* __restrict__ rgba,
    const float* __restrict__ tr, const float* __restrict__ rot,
    const float* __restrict__ sc, const float* __restrict__ sq,
    const float* __restrict__ sh, const float* __restrict__ re,
    const float* __restrict__ gr, const float* __restrict__ bl,
    float* __restrict__ dst)
{
    __shared__ float tb[BCHUNK][9];

    const int rem   = blockIdx.x % (SS * TILES_PER_S);
    const int chunk = blockIdx.x / (SS * TILES_PER_S);
    const int s     = rem / TILES_PER_S;
    const int tile  = rem % TILES_PER_S;
    const int tileY = tile / TPD;
    const int tileX = tile % TPD;

    const int tx = threadIdx.x & (TILE - 1);
    const int ty = threadIdx.x >> 4;
    const int w  = tileX * TILE + tx;
    const int h  = tileY * TILE + ty;

    setup_tb(tb, s, chunk, tr, rot, sc, sq, sh, re, gr, bl);
    __syncthreads();

    const float xs = -1.0f + 2.0f * (float)w / (float)(WW - 1);
    const float ys = -1.0f + 2.0f * (float)h / (float)(HH - 1);

    float accR = 0.0f, accG = 0.0f, accB = 0.0f;

    const float4* Ibase = rgba + (size_t)(s * BB + chunk * BCHUNK) * HW;

    for (int bb = 0; bb < BCHUNK; ++bb) {
        const float gx = tb[bb][0] * xs + tb[bb][1] * ys + tb[bb][2];
        const float gy = tb[bb][3] * xs + tb[bb][4] * ys + tb[bb][5];
        const float ix = (gx + 1.0f) * 0.5f * (float)(WW - 1);
        const float iy = (gy + 1.0f) * 0.5f * (float)(HH - 1);

        if (ix <= -1.0f || ix >= (float)WW || iy <= -1.0f || iy >= (float)HH) continue;

        const float ix0f = floorf(ix), iy0f = floorf(iy);
        const float wx = ix - ix0f, wy = iy - iy0f;
        const int ix0 = (int)ix0f, iy0 = (int)iy0f;

        const int x0 = max(ix0, 0);
        const int x1 = min(ix0 + 1, WW - 1);
        const int y0 = max(iy0, 0);
        const int y1 = min(iy0 + 1, HH - 1);

        const float vx0 = (ix0 >= 0)     ? 1.0f : 0.0f;
        const float vx1 = (ix0 + 1 < WW) ? 1.0f : 0.0f;
        const float vy0 = (iy0 >= 0)     ? 1.0f : 0.0f;
        const float vy1 = (iy0 + 1 < HH) ? 1.0f : 0.0f;

        const float w00 = (1.0f - wx) * (1.0f - wy) * vx0 * vy0;
        const float w01 = wx * (1.0f - wy) * vx1 * vy0;
        const float w10 = (1.0f - wx) * wy * vx0 * vy1;
        const float w11 = wx * wy * vx1 * vy1;

        const float4* Ib = Ibase + (size_t)bb * HW;
        const float4 v00 = Ib[y0 * WW + x0];
        const float4 v01 = Ib[y0 * WW + x1];
        const float4 v10 = Ib[y1 * WW + x0];
        const float4 v11 = Ib[y1 * WW + x1];

        const float cr = fmaf(v00.x, w00, fmaf(v01.x, w01, fmaf(v10.x, w10, v11.x * w11)));
        const float cg = fmaf(v00.y, w00, fmaf(v01.y, w01, fmaf(v10.y, w10, v11.y * w11)));
        const float cb = fmaf(v00.z, w00, fmaf(v01.z, w01, fmaf(v10.z, w10, v11.z * w11)));
        const float ca = fmaf(v00.w, w00, fmaf(v01.w, w01, fmaf(v10.w, w10, v11.w * w11)));

        accR = fmaf(cr * tb[bb][6], ca, accR);
        accG = fmaf(cg * tb[bb][7], ca, accG);
        accB = fmaf(cb * tb[bb][8], ca, accB);
    }

    const int pix = s * HW + h * WW + w;
    float* p = dst + (size_t)chunk * OUTN + (size_t)pix * 3;
    p[0] = accR; p[1] = accG; p[2] = accB;
}

// ---- main, planar fallback (ws too small for RGBA). WS=true -> partials, else atomics ----
template <bool MODE_WS>
__global__ __launch_bounds__(256) void k_main_planar(
    const float* __restrict__ patches,
    const float* __restrict__ tr, const float* __restrict__ rot,
    const float* __restrict__ sc, const float* __restrict__ sq,
    const float* __restrict__ sh, const float* __restrict__ re,
    const float* __restrict__ gr, const float* __restrict__ bl,
    float* __restrict__ dst)
{
    __shared__ float tb[BCHUNK][9];

    const int rem   = blockIdx.x % (SS * TILES_PER_S);
    const int chunk = blockIdx.x / (SS * TILES_PER_S);
    const int s     = rem / TILES_PER_S;
    const int tile  = rem % TILES_PER_S;
    const int tileY = tile / TPD;
    const int tileX = tile % TPD;

    const int tx = threadIdx.x & (TILE - 1);
    const int ty = threadIdx.x >> 4;
    const int w  = tileX * TILE + tx;
    const int h  = tileY * TILE + ty;

    setup_tb(tb, s, chunk, tr, rot, sc, sq, sh, re, gr, bl);
    __syncthreads();

    const float xs = -1.0f + 2.0f * (float)w / (float)(WW - 1);
    const float ys = -1.0f + 2.0f * (float)h / (float)(HH - 1);

    float accR = 0.0f, accG = 0.0f, accB = 0.0f;

    const float* Pbase = patches + (size_t)s * BB * CC * HW
                                 + (size_t)chunk * BCHUNK * CC * HW;

    for (int bb = 0; bb < BCHUNK; ++bb) {
        const float gx = tb[bb][0] * xs + tb[bb][1] * ys + tb[bb][2];
        const float gy = tb[bb][3] * xs + tb[bb][4] * ys + tb[bb][5];
        const float ix = (gx + 1.0f) * 0.5f * (float)(WW - 1);
        const float iy = (gy + 1.0f) * 0.5f * (float)(HH - 1);

        if (ix <= -1.0f || ix >= (float)WW || iy <= -1.0f || iy >= (float)HH) continue;

        const float ix0f = floorf(ix), iy0f = floorf(iy);
        const float wx = ix - ix0f, wy = iy - iy0f;
        const int ix0 = (int)ix0f, iy0 = (int)iy0f;

        const int x0 = max(ix0, 0);
        const int x1 = min(ix0 + 1, WW - 1);
        const int y0 = max(iy0, 0);
        const int y1 = min(iy0 + 1, HH - 1);

        const float vx0 = (ix0 >= 0)     ? 1.0f : 0.0f;
        const float vx1 = (ix0 + 1 < WW) ? 1.0f : 0.0f;
        const float vy0 = (iy0 >= 0)     ? 1.0f : 0.0f;
        const float vy1 = (iy0 + 1 < HH) ? 1.0f : 0.0f;

        const float w00 = (1.0f - wx) * (1.0f - wy) * vx0 * vy0;
        const float w01 = wx * (1.0f - wy) * vx1 * vy0;
        const float w10 = (1.0f - wx) * wy * vx0 * vy1;
        const float w11 = wx * wy * vx1 * vy1;

        const int i00 = y0 * WW + x0;
        const int i01 = y0 * WW + x1;
        const int i10 = y1 * WW + x0;
        const int i11 = y1 * WW + x1;

        const float* Pb = Pbase + (size_t)bb * CC * HW;

        float chv[4];
        #pragma unroll
        for (int c = 0; c < 4; ++c) {
            const float* Pc = Pb + (size_t)c * HW;
            chv[c] = Pc[i00] * w00 + Pc[i01] * w01 + Pc[i10] * w10 + Pc[i11] * w11;
        }
        const float alpha = chv[3];
        accR += chv[0] * tb[bb][6] * alpha;
        accG += chv[1] * tb[bb][7] * alpha;
        accB += chv[2] * tb[bb][8] * alpha;
    }

    const int pix = s * HW + h * WW + w;
    const size_t o = (size_t)pix * 3;
    if (MODE_WS) {
        float* p = dst + (size_t)chunk * OUTN + o;
        p[0] = accR; p[1] = accG; p[2] = accB;
    } else {
        atomicAdd(&dst[o + 0], accR);
        atomicAdd(&dst[o + 1], accG);
        atomicAdd(&dst[o + 2], accB);
    }
}

extern "C" void kernel_launch(void* const* d_in, const int* in_sizes, int n_in,
                              void* d_out, int out_size, void* d_ws, size_t ws_size,
                              hipStream_t stream) {
    const float* patches = (const float*)d_in[0];
    const float* tr      = (const float*)d_in[1];
    const float* rot     = (const float*)d_in[2];
    const float* sc      = (const float*)d_in[3];
    const float* sq      = (const float*)d_in[4];
    const float* sh      = (const float*)d_in[5];
    const float* re      = (const float*)d_in[6];
    const float* gr      = (const float*)d_in[7];
    const float* bl      = (const float*)d_in[8];
    // d_in[9] (orders) is mathematically dead: channel 4 never reaches the RGB output.
    float* out = (float*)d_out;

    const int nblkOut = (out_size + 255) / 256;
    const int grid    = SS * TILES_PER_S * NCHUNK;   // 3920
    float* wsf = (float*)d_ws;

    if (ws_size >= (RGBA_FLOATS + PART_FLOATS) * sizeof(float)) {
        // RGBA AoS path: repack -> gather dwordx4 -> reduce
        float4* rgba  = (float4*)wsf;
        float*  parts = wsf + RGBA_FLOATS;
        k_repack<<<IMGN * HW / 256, 256, 0, stream>>>(patches, rgba);
        k_main_rgba<<<grid, 256, 0, stream>>>(rgba, tr, rot, sc, sq, sh, re, gr, bl, parts);
        k_reduce<<<nblkOut, 256, 0, stream>>>(parts, out, out_size);
    } else if (ws_size >= PART_FLOATS * sizeof(float)) {
        k_main_planar<true><<<grid, 256, 0, stream>>>(patches, tr, rot, sc, sq, sh, re, gr, bl, wsf);
        k_reduce<<<nblkOut, 256, 0, stream>>>(wsf, out, out_size);
    } else {
        k_zero<<<nblkOut, 256, 0, stream>>>(out, out_size);
        k_main_planar<false><<<grid, 256, 0, stream>>>(patches, tr, rot, sc, sq, sh, re, gr, bl, out);
        k_clamp<<<nblkOut, 256, 0, stream>>>(out, out_size);
    }
}